// Round 1
// baseline (1685.802 us; speedup 1.0000x reference)
//
#include <hip/hip_runtime.h>
#include <float.h>

#define NT 32768
#define DIM 2048
#define NE 64
#define KC 64            // K chunk (floats)
#define TPW 8            // tokens per wave
#define NWAVES 8         // waves per block
#define TPB (TPW * NWAVES)  // 64 tokens per block

__global__ __launch_bounds__(512, 4)
void topk_router_kernel(const float* __restrict__ x,
                        const float* __restrict__ gw,
                        float* __restrict__ out) {
    // Swizzled w-chunk: ws[e*KC + ((c4 ^ (e&7))<<2) + j]
    __shared__ float ws[NE * KC];

    const int tid  = threadIdx.x;
    const int lane = tid & 63;          // lane == expert index
    const int wid  = tid >> 6;
    const int t0   = blockIdx.x * TPB + wid * TPW;

    float acc[TPW];
#pragma unroll
    for (int t = 0; t < TPW; ++t) acc[t] = 0.f;

    // staging mapping: 512 threads cover 64 rows x 64 floats (8 floats/thread)
    const int se  = tid >> 3;           // expert row 0..63
    const int sc8 = tid & 7;            // 8-float column group
    const int slot0 = ((2 * sc8)     ^ (se & 7)) << 2;
    const int slot1 = ((2 * sc8 + 1) ^ (se & 7)) << 2;
    const float* gwp = gw + (size_t)se * DIM + sc8 * 8;

    for (int k0 = 0; k0 < DIM; k0 += KC) {
        // issue staging loads early (overlap with previous chunk's compute)
        float4 r0 = *(const float4*)(gwp + k0);
        float4 r1 = *(const float4*)(gwp + k0 + 4);
        __syncthreads();                       // previous chunk's reads done
        *(float4*)&ws[se * KC + slot0] = r0;
        *(float4*)&ws[se * KC + slot1] = r1;
        __syncthreads();                       // chunk visible

        const float* xp = x + (size_t)t0 * DIM + k0;   // wave-uniform base
#pragma unroll
        for (int c4 = 0; c4 < KC / 4; ++c4) {
            float4 wv = *(const float4*)&ws[lane * KC + ((c4 ^ (lane & 7)) << 2)];
#pragma unroll
            for (int t = 0; t < TPW; ++t) {
                float4 xv = *(const float4*)(xp + t * DIM + c4 * 4); // uniform addr
                acc[t] = fmaf(wv.x, xv.x, acc[t]);
                acc[t] = fmaf(wv.y, xv.y, acc[t]);
                acc[t] = fmaf(wv.z, xv.z, acc[t]);
                acc[t] = fmaf(wv.w, xv.w, acc[t]);
            }
        }
    }

    // ---- epilogue: per-token top-2 across 64 lanes (lane == expert) ----
    float* mout = out;                                   // (NT, 64) mask
    float* wout = out + (size_t)NT * NE;                 // (NT, 2) weights
    float* iout = wout + (size_t)NT * 2;                 // (NT, 2) indices (as float)

#pragma unroll
    for (int t = 0; t < TPW; ++t) {
        const int tok = t0 + t;
        const float v = acc[t];

        // top-1, tie-break: lowest lane index
        float m1 = v; int i1 = lane;
#pragma unroll
        for (int off = 32; off >= 1; off >>= 1) {
            float ov = __shfl_xor(m1, off, 64);
            int   oi = __shfl_xor(i1, off, 64);
            if (ov > m1 || (ov == m1 && oi < i1)) { m1 = ov; i1 = oi; }
        }
        // top-2: mask out winner, reduce again
        float vm = (lane == i1) ? -FLT_MAX : v;
        float m2 = vm; int i2 = lane;
#pragma unroll
        for (int off = 32; off >= 1; off >>= 1) {
            float ov = __shfl_xor(m2, off, 64);
            int   oi = __shfl_xor(i2, off, 64);
            if (ov > m2 || (ov == m2 && oi < i2)) { m2 = ov; i2 = oi; }
        }

        // softmax over [m1, m2] (m1 >= m2, stable)
        float ed = expf(m2 - m1);
        float inv = 1.f / (1.f + ed);
        float p1 = inv;
        float p2 = ed * inv;

        // mask row: coalesced, one dword per lane
        mout[(size_t)tok * NE + lane] = (lane == i1 || lane == i2) ? 1.f : 0.f;

        if (lane == 0) {
            wout[2 * tok]     = p1;
            wout[2 * tok + 1] = p2;
            iout[2 * tok]     = (float)i1;
            iout[2 * tok + 1] = (float)i2;
        }
    }
}

extern "C" void kernel_launch(void* const* d_in, const int* in_sizes, int n_in,
                              void* d_out, int out_size, void* d_ws, size_t ws_size,
                              hipStream_t stream) {
    const float* x  = (const float*)d_in[0];
    const float* gw = (const float*)d_in[1];
    float* out = (float*)d_out;
    dim3 grid(NT / TPB);   // 512 blocks
    dim3 block(512);       // 8 waves
    topk_router_kernel<<<grid, block, 0, stream>>>(x, gw, out);
}

// Round 2
// 272.385 us; speedup vs baseline: 6.1890x; 6.1890x over previous
//
#include <hip/hip_runtime.h>
#include <float.h>

#define NT 32768
#define DIM 2048
#define NE 64
#define KC 64            // K-chunk (floats)
#define TPB 64           // tokens per block
#define NWAVES 4         // 256 threads
#define LSTR 68          // LDS row stride (KC + 4 pad -> conflict-free broadcasts)

__global__ __launch_bounds__(256, 3)
void topk_router_kernel(const float* __restrict__ x,
                        const float* __restrict__ gw,
                        float* __restrict__ out) {
    __shared__ float xs[TPB * LSTR];   // 64 tokens x 68
    __shared__ float wsh[NE * LSTR];   // 64 experts x 68

    const int tid  = threadIdx.x;
    const int lane = tid & 63;
    const int wid  = tid >> 6;
    const int tg   = lane >> 3;        // token group 0..7
    const int eg   = lane & 7;         // expert group 0..7
    const int tblock = blockIdx.x * TPB;

    // staging: 256 threads cover 64 rows x 16 float4 per chunk, 4 rows/thread
    const int srow = tid >> 4;          // 0..15
    const int scol = (tid & 15) * 4;    // float col 0..60
    const float* xg = x  + (size_t)(tblock + srow) * DIM + scol;
    const float* wg = gw + (size_t)srow * DIM + scol;

    float4 xr[4], wr[4];
#pragma unroll
    for (int r = 0; r < 4; ++r) {       // prologue: chunk 0 into regs
        xr[r] = *(const float4*)(xg + (size_t)(r * 16) * DIM);
        wr[r] = *(const float4*)(wg + (size_t)(r * 16) * DIM);
    }

    float acc[2][8];
#pragma unroll
    for (int i = 0; i < 2; ++i)
#pragma unroll
        for (int j = 0; j < 8; ++j) acc[i][j] = 0.f;

    const float* xbase = &xs[(wid * 16 + tg) * LSTR];
    const float* wbase = &wsh[eg * LSTR];

    for (int k0 = 0; k0 < DIM; k0 += KC) {
        __syncthreads();                        // prev chunk's reads done
#pragma unroll
        for (int r = 0; r < 4; ++r) {
            *(float4*)&xs [(srow + r * 16) * LSTR + scol] = xr[r];
            *(float4*)&wsh[(srow + r * 16) * LSTR + scol] = wr[r];
        }
        __syncthreads();                        // chunk visible

        if (k0 + KC < DIM) {                    // prefetch next chunk -> regs
#pragma unroll
            for (int r = 0; r < 4; ++r) {
                xr[r] = *(const float4*)(xg + (size_t)(r * 16) * DIM + k0 + KC);
                wr[r] = *(const float4*)(wg + (size_t)(r * 16) * DIM + k0 + KC);
            }
        }

#pragma unroll 4
        for (int c4 = 0; c4 < KC / 4; ++c4) {
            float4 xv0 = *(const float4*)(xbase + c4 * 4);
            float4 xv1 = *(const float4*)(xbase + 8 * LSTR + c4 * 4);
            float4 wv[8];
#pragma unroll
            for (int j = 0; j < 8; ++j)
                wv[j] = *(const float4*)(wbase + j * 8 * LSTR + c4 * 4);
#pragma unroll
            for (int j = 0; j < 8; ++j) {
                acc[0][j] = fmaf(xv0.x, wv[j].x, acc[0][j]);
                acc[0][j] = fmaf(xv0.y, wv[j].y, acc[0][j]);
                acc[0][j] = fmaf(xv0.z, wv[j].z, acc[0][j]);
                acc[0][j] = fmaf(xv0.w, wv[j].w, acc[0][j]);
                acc[1][j] = fmaf(xv1.x, wv[j].x, acc[1][j]);
                acc[1][j] = fmaf(xv1.y, wv[j].y, acc[1][j]);
                acc[1][j] = fmaf(xv1.z, wv[j].z, acc[1][j]);
                acc[1][j] = fmaf(xv1.w, wv[j].w, acc[1][j]);
            }
        }
    }

    // ---- epilogue: per-token top-2 over 64 experts (spread across 8 lanes) ----
    float* mout = out;                               // (NT,64) mask
    float* wout = out + (size_t)NT * NE;             // (NT,2) weights
    float* iout = wout + (size_t)NT * 2;             // (NT,2) indices (as float)

#pragma unroll
    for (int i = 0; i < 2; ++i) {
        const int tok = tblock + wid * 16 + tg + 8 * i;

        // local top-2 over this lane's 8 experts (e = eg + 8j, ascending)
        float m1 = -FLT_MAX, m2 = -FLT_MAX; int i1 = NE, i2 = NE;
#pragma unroll
        for (int j = 0; j < 8; ++j) {
            float v = acc[i][j]; int e = eg + 8 * j;
            if (v > m1)      { m2 = m1; i2 = i1; m1 = v; i1 = e; }
            else if (v > m2) { m2 = v; i2 = e; }
        }
        // butterfly merge across the 8 lanes sharing this token (xor 1,2,4)
#pragma unroll
        for (int off = 1; off <= 4; off <<= 1) {
            float om1 = __shfl_xor(m1, off, 64);
            int   oi1 = __shfl_xor(i1, off, 64);
            float om2 = __shfl_xor(m2, off, 64);
            int   oi2 = __shfl_xor(i2, off, 64);
            bool selfFirst = (m1 > om1) || (m1 == om1 && i1 < oi1);
            if (selfFirst) {
                bool keep = (m2 > om1) || (m2 == om1 && i2 < oi1);
                if (!keep) { m2 = om1; i2 = oi1; }
            } else {
                bool c = (m1 > om2) || (m1 == om2 && i1 < oi2);
                if (c) { m2 = m1; i2 = i1; } else { m2 = om2; i2 = oi2; }
                m1 = om1; i1 = oi1;
            }
        }

        // softmax over [m1, m2] (m1 >= m2)
        float ed  = expf(m2 - m1);
        float inv = 1.f / (1.f + ed);

        // mask: lane writes its contiguous 8-expert segment [eg*8, eg*8+8)
        float mv[8];
#pragma unroll
        for (int r = 0; r < 8; ++r) {
            int e = eg * 8 + r;
            mv[r] = (e == i1 || e == i2) ? 1.f : 0.f;
        }
        float* mrow = mout + (size_t)tok * NE + eg * 8;
        *(float4*)(mrow)     = make_float4(mv[0], mv[1], mv[2], mv[3]);
        *(float4*)(mrow + 4) = make_float4(mv[4], mv[5], mv[6], mv[7]);

        if (eg == 0) {
            *(float2*)(wout + 2 * tok) = make_float2(inv, ed * inv);
            *(float2*)(iout + 2 * tok) = make_float2((float)i1, (float)i2);
        }
    }
}

extern "C" void kernel_launch(void* const* d_in, const int* in_sizes, int n_in,
                              void* d_out, int out_size, void* d_ws, size_t ws_size,
                              hipStream_t stream) {
    const float* x  = (const float*)d_in[0];
    const float* gw = (const float*)d_in[1];
    float* out = (float*)d_out;
    dim3 grid(NT / TPB);   // 512 blocks
    dim3 block(NWAVES * 64);
    topk_router_kernel<<<grid, block, 0, stream>>>(x, gw, out);
}